// Round 1
// baseline (1846.300 us; speedup 1.0000x reference)
//
#include <hip/hip_runtime.h>

#define BATCH 32
#define CIN 64
#define HIN 128
#define WIN 128
#define COUT 128
#define HOUT 126
#define WOUT 126
#define HP 63
#define WP 63
#define NGROUPS 16
#define CPG 8
#define EPSV 1e-5f

#define TW 32
#define TH 8
#define ITW 34
#define ITH 10
#define NCO 8

// grid: x = tiles (4 in w * 16 in h), y = 16 cout-groups (== GN groups), z = batch
__global__ __launch_bounds__(256) void conv_stats_kernel(
    const float* __restrict__ x, const float* __restrict__ w,
    const float* __restrict__ bias, float* __restrict__ y,
    float* __restrict__ stats)
{
    __shared__ float sx[ITH][ITW];
    __shared__ float red[8];

    const int tid = threadIdx.x;
    const int tx = tid & 31;
    const int ty = tid >> 5;

    const int tile = blockIdx.x;
    const int tw0 = (tile & 3) * TW;
    const int th0 = (tile >> 2) * TH;
    const int g = blockIdx.y;
    const int cout0 = g * NCO;
    const int b = blockIdx.z;

    const float* xb = x + (size_t)b * CIN * (HIN * WIN);
    const float* wg = w + (size_t)cout0 * (CIN * 9);

    float acc[NCO];
#pragma unroll
    for (int i = 0; i < NCO; i++) acc[i] = 0.f;

    for (int cin = 0; cin < CIN; cin++) {
        const float* xc = xb + cin * (HIN * WIN);
        // stage 10x34 input tile
        for (int i = tid; i < ITH * ITW; i += 256) {
            int r = i / ITW;
            int c = i - r * ITW;
            int gy = th0 + r, gx = tw0 + c;
            float v = 0.f;
            if (gy < HIN && gx < WIN) v = xc[gy * WIN + gx];
            sx[r][c] = v;
        }
        __syncthreads();

        float v[3][3];
#pragma unroll
        for (int kh = 0; kh < 3; kh++)
#pragma unroll
            for (int kw = 0; kw < 3; kw++)
                v[kh][kw] = sx[ty + kh][tx + kw];

        const float* wc = wg + cin * 9;
#pragma unroll
        for (int co = 0; co < NCO; co++) {
            const float* wp = wc + co * (CIN * 9);
#pragma unroll
            for (int kh = 0; kh < 3; kh++)
#pragma unroll
                for (int kw = 0; kw < 3; kw++)
                    acc[co] = fmaf(v[kh][kw], wp[kh * 3 + kw], acc[co]);
        }
        __syncthreads();
    }

    const int oy = th0 + ty, ox = tw0 + tx;
    const bool valid = (oy < HOUT) && (ox < WOUT);

    float s = 0.f, ss = 0.f;
#pragma unroll
    for (int co = 0; co < NCO; co++) {
        float vv = acc[co] + bias[cout0 + co];
        acc[co] = vv;
        if (valid) { s += vv; ss += vv * vv; }
    }
    if (valid) {
        size_t base = (((size_t)b * COUT + cout0) * HOUT + oy) * WOUT + ox;
#pragma unroll
        for (int co = 0; co < NCO; co++)
            y[base + (size_t)co * (HOUT * WOUT)] = acc[co];
    }

    // block reduction of (s, ss)
#pragma unroll
    for (int off = 32; off > 0; off >>= 1) {
        s  += __shfl_down(s,  off, 64);
        ss += __shfl_down(ss, off, 64);
    }
    const int wave = tid >> 6, lane = tid & 63;
    if (lane == 0) { red[wave * 2] = s; red[wave * 2 + 1] = ss; }
    __syncthreads();
    if (tid == 0) {
        float S  = red[0] + red[2] + red[4] + red[6];
        float SS = red[1] + red[3] + red[5] + red[7];
        atomicAdd(&stats[(b * NGROUPS + g) * 2 + 0], S);
        atomicAdd(&stats[(b * NGROUPS + g) * 2 + 1], SS);
    }
}

__global__ __launch_bounds__(256) void norm_pool_kernel(
    const float* __restrict__ y, const float* __restrict__ stats,
    const float* __restrict__ gnw, const float* __restrict__ gnb,
    const float* __restrict__ scale, float* __restrict__ out)
{
    const int total = BATCH * COUT * HP * WP;
    int idx = blockIdx.x * 256 + threadIdx.x;
    if (idx >= total) return;

    int wp = idx % WP;
    int t = idx / WP;
    int hp = t % HP; t /= HP;
    int c = t % COUT;
    int b = t / COUT;
    int g = c / CPG;

    const float N = (float)(CPG * HOUT * WOUT);
    float sum   = stats[(b * NGROUPS + g) * 2 + 0];
    float sumsq = stats[(b * NGROUPS + g) * 2 + 1];
    float mean = sum / N;
    float var  = sumsq / N - mean * mean;
    float rstd = rsqrtf(var + EPSV);

    float A  = gnw[c] * rstd * scale[c];
    float B2 = (gnb[c] - mean * gnw[c] * rstd) * scale[c];

    const float* yp = y + (((size_t)b * COUT + c) * HOUT + hp * 2) * WOUT + wp * 2;
    float2 r0 = *(const float2*)yp;
    float2 r1 = *(const float2*)(yp + WOUT);

    float v0 = fmaf(r0.x, A, B2);
    float v1 = fmaf(r0.y, A, B2);
    float v2 = fmaf(r1.x, A, B2);
    float v3 = fmaf(r1.y, A, B2);
    float m = fmaxf(fmaxf(v0, v1), fmaxf(v2, v3));
    out[idx] = fminf(fmaxf(m, 0.0f), 1.0f);
}

extern "C" void kernel_launch(void* const* d_in, const int* in_sizes, int n_in,
                              void* d_out, int out_size, void* d_ws, size_t ws_size,
                              hipStream_t stream) {
    const float* x      = (const float*)d_in[0];
    const float* conv_w = (const float*)d_in[1];
    const float* conv_b = (const float*)d_in[2];
    const float* gnw    = (const float*)d_in[3];
    const float* gnb    = (const float*)d_in[4];
    const float* scale  = (const float*)d_in[5];
    float* out = (float*)d_out;

    const size_t y_bytes = (size_t)BATCH * COUT * HOUT * WOUT * sizeof(float);
    float* y     = (float*)d_ws;
    float* stats = (float*)((char*)d_ws + y_bytes);

    hipMemsetAsync(stats, 0, BATCH * NGROUPS * 2 * sizeof(float), stream);

    dim3 grid(64, NGROUPS, BATCH);
    conv_stats_kernel<<<grid, 256, 0, stream>>>(x, conv_w, conv_b, y, stats);

    const int total = BATCH * COUT * HP * WP;
    norm_pool_kernel<<<(total + 255) / 256, 256, 0, stream>>>(y, stats, gnw, gnb, scale, out);
}

// Round 2
// 462.357 us; speedup vs baseline: 3.9932x; 3.9932x over previous
//
#include <hip/hip_runtime.h>

typedef _Float16 half8 __attribute__((ext_vector_type(8)));
typedef _Float16 half2t __attribute__((ext_vector_type(2)));
typedef float float4t __attribute__((ext_vector_type(4)));

#define BATCH 32
#define CIN 64
#define HIN 128
#define WIN 128
#define COUT 128
#define HOUT 126
#define WOUT 126
#define HP 63
#define WP 63
#define NGROUPS 16
#define CPG 8
#define EPSV 1e-5f

#define XS_COLS 130
#define XS_CSTR 72   // cin stride in fp16 elems = 144B (16B multiple -> aligned b128, odd dword-ish banking)

// wT[pos][cout][cin] fp16, pos = kh*3+kw
__global__ __launch_bounds__(256) void wt_kernel(const float* __restrict__ w,
                                                 _Float16* __restrict__ wT) {
    int idx = blockIdx.x * 256 + threadIdx.x;
    if (idx >= 9 * COUT * CIN) return;
    int cin = idx & 63;
    int t = idx >> 6;
    int cout = t & 127;
    int pos = t >> 7;
    wT[idx] = (_Float16)w[(cout * CIN + cin) * 9 + pos];
}

// grid: x = oy (126), y = b (32). Block: 256 thr = 4 waves; wave w -> couts w*32..w*32+31.
__global__ __launch_bounds__(256, 2) void conv_mfma_kernel(
    const float* __restrict__ x, const _Float16* __restrict__ wT,
    const float* __restrict__ bias, float* __restrict__ y,
    float* __restrict__ stats)
{
    __shared__ __align__(16) _Float16 xs[3 * XS_COLS * XS_CSTR];

    const int tid = threadIdx.x;
    const int oy = blockIdx.x;
    const int b  = blockIdx.y;

    // ---- stage xs[r][col][cin] = fp16(x[b][cin][oy+r][col]), once per block ----
    {
        const int cp  = tid & 31;        // cin pair -> cins {2cp, 2cp+1}
        const int seg = tid >> 5;        // col segment of 16
        const int c0  = 2 * cp;
        const float* xb = x + (size_t)b * CIN * (HIN * WIN);
        for (int i = 0; i < 12; i++) {
            int r = i >> 2;
            int col4 = seg * 16 + (i & 3) * 4;
            const float* p0 = xb + ((size_t)c0 * HIN + (oy + r)) * WIN + col4;
            const float* p1 = p0 + (size_t)HIN * WIN;
            float4t va = *(const float4t*)p0;
            float4t vb = *(const float4t*)p1;
            _Float16* dst = &xs[(r * XS_COLS + col4) * XS_CSTR + c0];
#pragma unroll
            for (int j = 0; j < 4; j++) {
                half2t hv = { (_Float16)va[j], (_Float16)vb[j] };
                *(half2t*)(dst + j * XS_CSTR) = hv;   // ds_write_b32, lanes = consecutive cins: conflict-free
            }
        }
        // zero pad cols 128,129 (read when pixel>=126, masked at store but must be finite)
        if (tid < 192) {
            int cpz = tid & 31;
            int colx = (tid >> 5) & 1;
            int r = tid >> 6;
            half2t z = { (_Float16)0.f, (_Float16)0.f };
            *(half2t*)&xs[(r * XS_COLS + 128 + colx) * XS_CSTR + 2 * cpz] = z;
        }
    }
    __syncthreads();

    const int lane = tid & 63;
    const int wv   = tid >> 6;
    const int m    = lane & 15;       // A-row / D-col index
    const int q    = lane >> 4;       // quad
    const int cout0 = wv * 32;

    float4t acc[2][8];
#pragma unroll
    for (int s = 0; s < 2; s++)
#pragma unroll
        for (int n = 0; n < 8; n++)
            acc[s][n] = (float4t){0.f, 0.f, 0.f, 0.f};

    // K-loop: 9 (kh,kw) positions x 2 cin-halves. A prefetched from global wT (L2-hot).
    const _Float16* ab0 = wT + (size_t)(cout0 + m) * CIN + q * 8;
    half8 a0 = *(const half8*)(ab0);
    half8 a1 = *(const half8*)(ab0 + 16 * CIN);

    for (int kk = 0; kk < 18; kk++) {
        int pos = kk >> 1, ch = kk & 1;
        int kh = (pos > 2) + (pos > 5);
        int kw = pos - kh * 3;
        const _Float16* bb = &xs[(kh * XS_COLS + m + kw) * XS_CSTR + q * 8 + ch * 32];

        half8 na0 = a0, na1 = a1;
        if (kk < 17) {
            int nk = kk + 1, npos = nk >> 1, nch = nk & 1;
            const _Float16* ab = wT + ((size_t)(npos * COUT + cout0 + m)) * CIN + q * 8 + nch * 32;
            na0 = *(const half8*)ab;
            na1 = *(const half8*)(ab + 16 * CIN);
        }
#pragma unroll
        for (int n = 0; n < 8; n++) {
            half8 bf = *(const half8*)(bb + n * 16 * XS_CSTR);
            acc[0][n] = __builtin_amdgcn_mfma_f32_16x16x32_f16(a0, bf, acc[0][n], 0, 0, 0);
            acc[1][n] = __builtin_amdgcn_mfma_f32_16x16x32_f16(a1, bf, acc[1][n], 0, 0, 0);
        }
        a0 = na0; a1 = na1;
    }

    // ---- epilogue: bias, store y (fp32), per-group stats ----
    float sv[2] = {0.f, 0.f}, ssv[2] = {0.f, 0.f};
    float bvals[2][4];
#pragma unroll
    for (int sub = 0; sub < 2; sub++)
#pragma unroll
        for (int reg = 0; reg < 4; reg++)
            bvals[sub][reg] = bias[cout0 + sub * 16 + q * 4 + reg];

#pragma unroll
    for (int sub = 0; sub < 2; sub++) {
#pragma unroll
        for (int n = 0; n < 8; n++) {
            int pix = n * 16 + m;
            bool valid = pix < WOUT;
            float* yp = y + (((size_t)b * COUT + cout0 + sub * 16 + q * 4) * HOUT + oy) * WOUT + pix;
#pragma unroll
            for (int reg = 0; reg < 4; reg++) {
                float v = acc[sub][n][reg] + bvals[sub][reg];
                if (valid) {
                    yp[(size_t)reg * HOUT * WOUT] = v;
                    sv[sub] += v;
                    ssv[sub] += v * v;
                }
            }
        }
    }
    // halves of the wave hold disjoint GN groups: lanes 0..31 -> group sub*2+0, 32..63 -> +1
#pragma unroll
    for (int sub = 0; sub < 2; sub++) {
        float a = sv[sub], c = ssv[sub];
        for (int off = 16; off; off >>= 1) {
            a += __shfl_down(a, off, 32);
            c += __shfl_down(c, off, 32);
        }
        if ((lane & 31) == 0) {
            int g = wv * 4 + sub * 2 + (lane >> 5);
            atomicAdd(&stats[(b * NGROUPS + g) * 2 + 0], a);
            atomicAdd(&stats[(b * NGROUPS + g) * 2 + 1], c);
        }
    }
}

__global__ __launch_bounds__(256) void norm_pool_kernel(
    const float* __restrict__ y, const float* __restrict__ stats,
    const float* __restrict__ gnw, const float* __restrict__ gnb,
    const float* __restrict__ scale, float* __restrict__ out)
{
    const int total = BATCH * COUT * HP * WP;
    int idx = blockIdx.x * 256 + threadIdx.x;
    if (idx >= total) return;

    int wp = idx % WP;
    int t = idx / WP;
    int hp = t % HP; t /= HP;
    int c = t % COUT;
    int b = t / COUT;
    int g = c / CPG;

    const float N = (float)(CPG * HOUT * WOUT);
    float sum   = stats[(b * NGROUPS + g) * 2 + 0];
    float sumsq = stats[(b * NGROUPS + g) * 2 + 1];
    float mean = sum / N;
    float var  = sumsq / N - mean * mean;
    float rstd = rsqrtf(var + EPSV);

    float A  = gnw[c] * rstd * scale[c];
    float B2 = (gnb[c] - mean * gnw[c] * rstd) * scale[c];

    const float* yp = y + (((size_t)b * COUT + c) * HOUT + hp * 2) * WOUT + wp * 2;
    float2 r0 = *(const float2*)yp;
    float2 r1 = *(const float2*)(yp + WOUT);

    float v0 = fmaf(r0.x, A, B2);
    float v1 = fmaf(r0.y, A, B2);
    float v2 = fmaf(r1.x, A, B2);
    float v3 = fmaf(r1.y, A, B2);
    float mx = fmaxf(fmaxf(v0, v1), fmaxf(v2, v3));
    out[idx] = fminf(fmaxf(mx, 0.0f), 1.0f);
}

extern "C" void kernel_launch(void* const* d_in, const int* in_sizes, int n_in,
                              void* d_out, int out_size, void* d_ws, size_t ws_size,
                              hipStream_t stream) {
    const float* x      = (const float*)d_in[0];
    const float* conv_w = (const float*)d_in[1];
    const float* conv_b = (const float*)d_in[2];
    const float* gnw    = (const float*)d_in[3];
    const float* gnb    = (const float*)d_in[4];
    const float* scale  = (const float*)d_in[5];
    float* out = (float*)d_out;

    const size_t y_bytes = (size_t)BATCH * COUT * HOUT * WOUT * sizeof(float);
    float* y     = (float*)d_ws;
    float* stats = (float*)((char*)d_ws + y_bytes);
    _Float16* wT = (_Float16*)((char*)d_ws + y_bytes + 4096);

    hipMemsetAsync(stats, 0, BATCH * NGROUPS * 2 * sizeof(float), stream);

    wt_kernel<<<(9 * COUT * CIN + 255) / 256, 256, 0, stream>>>(conv_w, wT);

    dim3 grid(HOUT, BATCH);
    conv_mfma_kernel<<<grid, 256, 0, stream>>>(x, wT, conv_b, y, stats);

    const int total = BATCH * COUT * HP * WP;
    norm_pool_kernel<<<(total + 255) / 256, 256, 0, stream>>>(y, stats, gnw, gnb, scale, out);
}